// Round 9
// baseline (334.321 us; speedup 1.0000x reference)
//
#include <hip/hip_runtime.h>
#include <hip/hip_bf16.h>

// Problem constants
#define BATCH 16384
#define K1DIM 3072
#define NCOUNT 8
#define NO 16            // L2+1 outputs of layer-1 per selected stack
#define CHUNK 256        // floats of K per staged chunk (16 rows x 1 KB = 16 KB)
#define NCHUNK (K1DIM / CHUNK)   // 12
#define SPB 16           // samples per block (4 per wave)

typedef float f32x4 __attribute__((ext_vector_type(4)));
typedef unsigned int u32;

__host__ __device__ constexpr int brev6(int i) {
    int r = 0;
    for (int b = 0; b < 6; ++b) r |= ((i >> b) & 1) << (5 - b);
    return r;
}

// ---------------- K0: precombine weights  wc = l1_w[stack] + l1f_w --------
__global__ __launch_bounds__(256) void k_combine(const float* __restrict__ l1w,
                                                 const float* __restrict__ l1fw,
                                                 float* __restrict__ wc) {
    int i = blockIdx.x * 256 + threadIdx.x;   // float4 index, 98304 total
    int row = i / 768;                        // 0..127  (stack*16 + o)
    int col = (i - row * 768) * 4;            // float col
    int o = row & 15;
    f32x4 a = *(const f32x4*)(l1w + (size_t)row * K1DIM + col);
    f32x4 f = *(const f32x4*)(l1fw + (size_t)o * K1DIM + col);
    *(f32x4*)(wc + (size_t)row * K1DIM + col) = a + f;
}

// ---------------- K1: bucket samples by idx (LDS histogram) ----------------
__global__ __launch_bounds__(256) void k_bucket(const int* __restrict__ ls,
                                                int* __restrict__ counts,
                                                int* __restrict__ bucketArr) {
    __shared__ int h[NCOUNT];
    __shared__ int hbase[NCOUNT];
    int t = threadIdx.x;
    if (t < NCOUNT) h[t] = 0;
    __syncthreads();
    int i = blockIdx.x * 256 + t;
    int idx = ls[i];
    int lpos = atomicAdd(&h[idx], 1);
    __syncthreads();
    if (t < NCOUNT) hbase[t] = atomicAdd(&counts[t], h[t]);
    __syncthreads();
    bucketArr[idx * BATCH + hbase[idx] + lpos] = i;
}

// ---------------- K3: main gather-GEMM  y[s][0..15] ------------------------
// 16 samples/block (4 per wave), K on lanes. Weights staged to LDS via async
// global_load_lds (16 KB chunk, double-buffered); x prefetched one chunk
// ahead into registers. 4 waves/SIMD (VGPR<=128) cover remaining latency.
__device__ __forceinline__ void stage4(const float* gbase, float* lds_linear,
                                       int wid, int lane) {
#pragma unroll
    for (int i = 0; i < 4; ++i) {
        int row = wid * 4 + i;
        const float* g = gbase + (size_t)row * K1DIM + lane * 4;
        float* l = lds_linear + row * CHUNK;   // wave-uniform base; HW adds lane*16
        __builtin_amdgcn_global_load_lds(
            (const __attribute__((address_space(1))) u32*)g,
            (__attribute__((address_space(3))) u32*)l, 16, 0, 0);
    }
}

__global__ __launch_bounds__(256, 4) void k_gemm(
    const float* __restrict__ x, const float* __restrict__ wc_all,
    const float* __restrict__ l1b, const float* __restrict__ l1fb,
    const int* __restrict__ bucketArr, const int* __restrict__ counts,
    float* __restrict__ y) {
    __shared__ float buf[2][NO * CHUNK];   // 2 x 16 KB

    // per-block prefix over bucket counts
    int cnt[NCOUNT], off[NCOUNT];
    int nblk = 0;
#pragma unroll
    for (int i = 0; i < NCOUNT; ++i) {
        cnt[i] = counts[i];
        off[i] = nblk;
        nblk += (cnt[i] + SPB - 1) / SPB;
    }
    int b = blockIdx.x;
    if (b >= nblk) return;
    int bucket = 0;
#pragma unroll
    for (int i = 1; i < NCOUNT; ++i) if (b >= off[i]) bucket = i;
    int chunkblk = b - off[bucket];
    int count = cnt[bucket];

    int t = threadIdx.x;
    int lane = t & 63;
    int wid = t >> 6;

    const int* bk = bucketArr + bucket * BATCH;
    int base = chunkblk * SPB + wid * 4;
    const float* xr[4];
#pragma unroll
    for (int j = 0; j < 4; ++j) {
        int g = min(base + j, count - 1);
        xr[j] = x + (size_t)bk[g] * K1DIM + lane * 4;
    }
    const float* wstack = wc_all + (size_t)bucket * NO * K1DIM;

    float acc[64];
#pragma unroll
    for (int i = 0; i < 64; ++i) acc[i] = 0.f;

    stage4(wstack, &buf[0][0], wid, lane);   // chunk 0 -> buf[0]

    f32x4 xv[4];
#pragma unroll
    for (int j = 0; j < 4; ++j) xv[j] = *(const f32x4*)(xr[j]);   // x chunk 0

    for (int it = 0; it < NCHUNK; ++it) {
        int cur = it & 1;
        __syncthreads();                     // buf[cur] staged
        f32x4 xvn[4];
        if (it + 1 < NCHUNK) {
            stage4(wstack + (it + 1) * CHUNK, &buf[cur ^ 1][0], wid, lane);
            int kn = (it + 1) * CHUNK;
#pragma unroll
            for (int j = 0; j < 4; ++j) xvn[j] = *(const f32x4*)(xr[j] + kn);
        }
        const float* lb = &buf[cur][lane * 4];
#pragma unroll
        for (int o = 0; o < NO; ++o) {
            f32x4 wv = *(const f32x4*)(lb + o * CHUNK);
#define ACCUM(S)                                                         \
            {                                                            \
                float& a_ = acc[brev6((S)*16 + o)];                      \
                a_ = fmaf(xv[S].x, wv.x, a_);                            \
                a_ = fmaf(xv[S].y, wv.y, a_);                            \
                a_ = fmaf(xv[S].z, wv.z, a_);                            \
                a_ = fmaf(xv[S].w, wv.w, a_);                            \
            }
            ACCUM(0) ACCUM(1) ACCUM(2) ACCUM(3)
#undef ACCUM
        }
        if (it + 1 < NCHUNK) {
#pragma unroll
            for (int j = 0; j < 4; ++j) xv[j] = xvn[j];
        }
    }

    // 6-stage butterfly: lane l ends holding pair l (sample l>>4, output l&15)
#pragma unroll
    for (int st = 0; st < 6; ++st) {
        const int m = 1 << st;
        const int half = 32 >> st;
        const bool hi = (lane & m) != 0;
#pragma unroll
        for (int i = 0; i < half; ++i) {
            float mine = hi ? acc[i] : acc[i + half];
            float other = __shfl_xor(mine, m, 64);
            float keep = hi ? acc[i + half] : acc[i];
            acc[i] = keep + other;
        }
    }

    int p_s = lane >> 4;
    int p_o = lane & 15;
    int gp = min(base + p_s, count - 1);
    int sid = bk[gp];
    float bias = l1b[bucket * NO + p_o] + l1fb[p_o];
    y[(size_t)sid * NO + p_o] = acc[0] + bias;
}

// ---------------- K4: tail MLP (30 -> 32 -> 1), 32 lanes per sample --------
__global__ __launch_bounds__(256) void k_tail(
    const float* __restrict__ y, const int* __restrict__ ls,
    const float* __restrict__ l2w, const float* __restrict__ l2b,
    const float* __restrict__ outw, const float* __restrict__ outb,
    float* __restrict__ out) {
    int gt = blockIdx.x * 256 + threadIdx.x;
    int s = gt >> 5;           // sample
    int o2 = gt & 31;          // hidden unit
    int idx = ls[s];
    const f32x4* yp = (const f32x4*)(y + (size_t)s * NO);
    f32x4 a0 = yp[0], a1 = yp[1], a2 = yp[2], a3 = yp[3];
    float v[16] = {a0.x, a0.y, a0.z, a0.w, a1.x, a1.y, a1.z, a1.w,
                   a2.x, a2.y, a2.z, a2.w, a3.x, a3.y, a3.z, a3.w};
    float l1x[30];
#pragma unroll
    for (int j = 0; j < 15; ++j) {
        float tv = v[j];
        float sq = tv * tv * (127.f / 128.f);
        l1x[j] = fminf(fmaxf(sq, 0.f), 1.f);
        l1x[j + 15] = fminf(fmaxf(tv, 0.f), 1.f);
    }
    const float* wr = l2w + (size_t)idx * 32 * 30 + o2 * 30;
    float tacc = l2b[idx * 32 + o2];
#pragma unroll
    for (int j = 0; j < 15; ++j) {
        float2 wpv = *(const float2*)(wr + j * 2);
        tacc = fmaf(l1x[j * 2], wpv.x, tacc);
        tacc = fmaf(l1x[j * 2 + 1], wpv.y, tacc);
    }
    tacc = fminf(fmaxf(tacc, 0.f), 1.f);
    float r = tacc * outw[idx * 32 + o2];
#pragma unroll
    for (int m = 1; m < 32; m <<= 1) r += __shfl_xor(r, m, 64);
    if (o2 == 0) out[s] = r + outb[idx] + v[15];
}

// ---------------- launch ---------------------------------------------------
extern "C" void kernel_launch(void* const* d_in, const int* in_sizes, int n_in,
                              void* d_out, int out_size, void* d_ws, size_t ws_size,
                              hipStream_t stream) {
    const float* x    = (const float*)d_in[0];
    const int*   ls   = (const int*)  d_in[1];
    const float* l1w  = (const float*)d_in[2];
    const float* l1b  = (const float*)d_in[3];
    const float* l1fw = (const float*)d_in[4];
    const float* l1fb = (const float*)d_in[5];
    const float* l2w  = (const float*)d_in[6];
    const float* l2b  = (const float*)d_in[7];
    const float* outw = (const float*)d_in[8];
    const float* outb = (const float*)d_in[9];
    float* out = (float*)d_out;

    char* ws = (char*)d_ws;
    float* wc       = (float*)ws;                       // 128*3072*4 = 1.5 MB
    float* y        = (float*)(ws + 1572864);           // 16384*16*4 = 1 MB
    int*   bucketArr= (int*)(ws + 1572864 + 1048576);   // 8*16384*4 = 512 KB
    int*   counts   = (int*)(ws + 1572864 + 1048576 + 524288);

    (void)hipMemsetAsync(counts, 0, 32, stream);
    k_combine<<<384, 256, 0, stream>>>(l1w, l1fw, wc);
    k_bucket<<<BATCH / 256, 256, 0, stream>>>(ls, counts, bucketArr);
    // max blocks = 16384/16 + 7 (ceil rounding across 8 buckets)
    k_gemm<<<1031, 256, 0, stream>>>(x, wc, l1b, l1fb, bucketArr, counts, y);
    k_tail<<<BATCH * 32 / 256, 256, 0, stream>>>(y, ls, l2w, l2b, outw, outb, out);
}

// Round 10
// 320.876 us; speedup vs baseline: 1.0419x; 1.0419x over previous
//
#include <hip/hip_runtime.h>
#include <hip/hip_bf16.h>

// Problem constants
#define BATCH 16384
#define K1DIM 3072
#define NCOUNT 8
#define NO 16            // L2+1 outputs of layer-1 per selected stack
#define CHUNK 256        // floats of K per staged chunk (16 rows x 1 KB = 16 KB)
#define NCHUNK (K1DIM / CHUNK)   // 12
#define SPB 16           // samples per block (4 per wave)

typedef float f32x4 __attribute__((ext_vector_type(4)));
typedef unsigned int u32;

__host__ __device__ constexpr int brev6(int i) {
    int r = 0;
    for (int b = 0; b < 6; ++b) r |= ((i >> b) & 1) << (5 - b);
    return r;
}

// ---------------- K0: precombine weights  wc = l1_w[stack] + l1f_w --------
__global__ __launch_bounds__(256) void k_combine(const float* __restrict__ l1w,
                                                 const float* __restrict__ l1fw,
                                                 float* __restrict__ wc) {
    int i = blockIdx.x * 256 + threadIdx.x;   // float4 index, 98304 total
    int row = i / 768;                        // 0..127  (stack*16 + o)
    int col = (i - row * 768) * 4;            // float col
    int o = row & 15;
    f32x4 a = *(const f32x4*)(l1w + (size_t)row * K1DIM + col);
    f32x4 f = *(const f32x4*)(l1fw + (size_t)o * K1DIM + col);
    *(f32x4*)(wc + (size_t)row * K1DIM + col) = a + f;
}

// ---------------- K1: bucket samples by idx (LDS histogram) ----------------
__global__ __launch_bounds__(256) void k_bucket(const int* __restrict__ ls,
                                                int* __restrict__ counts,
                                                int* __restrict__ bucketArr) {
    __shared__ int h[NCOUNT];
    __shared__ int hbase[NCOUNT];
    int t = threadIdx.x;
    if (t < NCOUNT) h[t] = 0;
    __syncthreads();
    int i = blockIdx.x * 256 + t;
    int idx = ls[i];
    int lpos = atomicAdd(&h[idx], 1);
    __syncthreads();
    if (t < NCOUNT) hbase[t] = atomicAdd(&counts[t], h[t]);
    __syncthreads();
    bucketArr[idx * BATCH + hbase[idx] + lpos] = i;
}

// ---------------- K3: main gather-GEMM  y[s][0..15] ------------------------
// 16 samples/block (4 per wave), K on lanes. Weights staged to LDS via async
// global_load_lds (16 KB chunk, double-buffered); x prefetched one chunk
// ahead. Counted-vmcnt barrier (T4): stage ops drained, x loads stay in
// flight across the barrier — no vmcnt(0) full drain in the main loop.
__device__ __forceinline__ void stage4(const float* gbase, float* lds_linear,
                                       int wid, int lane) {
#pragma unroll
    for (int i = 0; i < 4; ++i) {
        int row = wid * 4 + i;
        const float* g = gbase + (size_t)row * K1DIM + lane * 4;
        float* l = lds_linear + row * CHUNK;   // wave-uniform base; HW adds lane*16
        __builtin_amdgcn_global_load_lds(
            (const __attribute__((address_space(1))) u32*)g,
            (__attribute__((address_space(3))) u32*)l, 16, 0, 0);
    }
}

__global__ __launch_bounds__(256, 4) void k_gemm(
    const float* __restrict__ x, const float* __restrict__ wc_all,
    const float* __restrict__ l1b, const float* __restrict__ l1fb,
    const int* __restrict__ bucketArr, const int* __restrict__ counts,
    float* __restrict__ y) {
    __shared__ float buf[2][NO * CHUNK];   // 2 x 16 KB

    // per-block prefix over bucket counts
    int cnt[NCOUNT], off[NCOUNT];
    int nblk = 0;
#pragma unroll
    for (int i = 0; i < NCOUNT; ++i) {
        cnt[i] = counts[i];
        off[i] = nblk;
        nblk += (cnt[i] + SPB - 1) / SPB;
    }
    int b = blockIdx.x;
    if (b >= nblk) return;
    int bucket = 0;
#pragma unroll
    for (int i = 1; i < NCOUNT; ++i) if (b >= off[i]) bucket = i;
    int chunkblk = b - off[bucket];
    int count = cnt[bucket];

    int t = threadIdx.x;
    int lane = t & 63;
    int wid = t >> 6;

    const int* bk = bucketArr + bucket * BATCH;
    int base = chunkblk * SPB + wid * 4;
    const float* xr[4];
#pragma unroll
    for (int j = 0; j < 4; ++j) {
        int g = min(base + j, count - 1);
        xr[j] = x + (size_t)bk[g] * K1DIM + lane * 4;
    }
    const float* wstack = wc_all + (size_t)bucket * NO * K1DIM;

    float acc[64];
#pragma unroll
    for (int i = 0; i < 64; ++i) acc[i] = 0.f;

    // prologue: stage chunk 0, full drain, then issue x chunk 0
    stage4(wstack, &buf[0][0], wid, lane);
    asm volatile("s_waitcnt vmcnt(0)\n\ts_barrier" ::: "memory");
    __builtin_amdgcn_sched_barrier(0);

    f32x4 xv[4];
#pragma unroll
    for (int j = 0; j < 4; ++j) xv[j] = *(const f32x4*)(xr[j]);   // x chunk 0

    for (int it = 0; it < NCHUNK; ++it) {
        int cur = it & 1;
        // A: stage next chunk (4 VMEM ops) — issued FIRST
        if (it + 1 < NCHUNK)
            stage4(wstack + (it + 1) * CHUNK, &buf[cur ^ 1][0], wid, lane);
        __builtin_amdgcn_sched_barrier(0);
        // B: x prefetch next chunk (4 VMEM ops) — issued AFTER stage
        f32x4 xvn[4];
        if (it + 1 < NCHUNK) {
            int kn = (it + 1) * CHUNK;
#pragma unroll
            for (int j = 0; j < 4; ++j) xvn[j] = *(const f32x4*)(xr[j] + kn);
        }
        __builtin_amdgcn_sched_barrier(0);
        // C: compute on buf[cur] with xv (regs loaded last iter)
        const float* lb = &buf[cur][lane * 4];
#pragma unroll
        for (int o = 0; o < NO; ++o) {
            f32x4 wv = *(const f32x4*)(lb + o * CHUNK);
#define ACCUM(S)                                                         \
            {                                                            \
                float& a_ = acc[brev6((S)*16 + o)];                      \
                a_ = fmaf(xv[S].x, wv.x, a_);                            \
                a_ = fmaf(xv[S].y, wv.y, a_);                            \
                a_ = fmaf(xv[S].z, wv.z, a_);                            \
                a_ = fmaf(xv[S].w, wv.w, a_);                            \
            }
            ACCUM(0) ACCUM(1) ACCUM(2) ACCUM(3)
#undef ACCUM
        }
        // D/E: counted barrier — drain my 4 stage ops (oldest of the 8 in
        // flight) + all LDS reads; leave the 4 x loads flying across.
        if (it + 1 < NCHUNK) {
            __builtin_amdgcn_sched_barrier(0);
            asm volatile("s_waitcnt vmcnt(4) lgkmcnt(0)\n\ts_barrier" ::: "memory");
            __builtin_amdgcn_sched_barrier(0);
#pragma unroll
            for (int j = 0; j < 4; ++j) xv[j] = xvn[j];
        }
    }

    // 6-stage butterfly: lane l ends holding pair l (sample l>>4, output l&15)
#pragma unroll
    for (int st = 0; st < 6; ++st) {
        const int m = 1 << st;
        const int half = 32 >> st;
        const bool hi = (lane & m) != 0;
#pragma unroll
        for (int i = 0; i < half; ++i) {
            float mine = hi ? acc[i] : acc[i + half];
            float other = __shfl_xor(mine, m, 64);
            float keep = hi ? acc[i + half] : acc[i];
            acc[i] = keep + other;
        }
    }

    int p_s = lane >> 4;
    int p_o = lane & 15;
    int gp = min(base + p_s, count - 1);
    int sid = bk[gp];
    float bias = l1b[bucket * NO + p_o] + l1fb[p_o];
    y[(size_t)sid * NO + p_o] = acc[0] + bias;
}

// ---------------- K4: tail MLP (30 -> 32 -> 1), 32 lanes per sample --------
__global__ __launch_bounds__(256) void k_tail(
    const float* __restrict__ y, const int* __restrict__ ls,
    const float* __restrict__ l2w, const float* __restrict__ l2b,
    const float* __restrict__ outw, const float* __restrict__ outb,
    float* __restrict__ out) {
    int gt = blockIdx.x * 256 + threadIdx.x;
    int s = gt >> 5;           // sample
    int o2 = gt & 31;          // hidden unit
    int idx = ls[s];
    const f32x4* yp = (const f32x4*)(y + (size_t)s * NO);
    f32x4 a0 = yp[0], a1 = yp[1], a2 = yp[2], a3 = yp[3];
    float v[16] = {a0.x, a0.y, a0.z, a0.w, a1.x, a1.y, a1.z, a1.w,
                   a2.x, a2.y, a2.z, a2.w, a3.x, a3.y, a3.z, a3.w};
    float l1x[30];
#pragma unroll
    for (int j = 0; j < 15; ++j) {
        float tv = v[j];
        float sq = tv * tv * (127.f / 128.f);
        l1x[j] = fminf(fmaxf(sq, 0.f), 1.f);
        l1x[j + 15] = fminf(fmaxf(tv, 0.f), 1.f);
    }
    const float* wr = l2w + (size_t)idx * 32 * 30 + o2 * 30;
    float tacc = l2b[idx * 32 + o2];
#pragma unroll
    for (int j = 0; j < 15; ++j) {
        float2 wpv = *(const float2*)(wr + j * 2);
        tacc = fmaf(l1x[j * 2], wpv.x, tacc);
        tacc = fmaf(l1x[j * 2 + 1], wpv.y, tacc);
    }
    tacc = fminf(fmaxf(tacc, 0.f), 1.f);
    float r = tacc * outw[idx * 32 + o2];
#pragma unroll
    for (int m = 1; m < 32; m <<= 1) r += __shfl_xor(r, m, 64);
    if (o2 == 0) out[s] = r + outb[idx] + v[15];
}

// ---------------- launch ---------------------------------------------------
extern "C" void kernel_launch(void* const* d_in, const int* in_sizes, int n_in,
                              void* d_out, int out_size, void* d_ws, size_t ws_size,
                              hipStream_t stream) {
    const float* x    = (const float*)d_in[0];
    const int*   ls   = (const int*)  d_in[1];
    const float* l1w  = (const float*)d_in[2];
    const float* l1b  = (const float*)d_in[3];
    const float* l1fw = (const float*)d_in[4];
    const float* l1fb = (const float*)d_in[5];
    const float* l2w  = (const float*)d_in[6];
    const float* l2b  = (const float*)d_in[7];
    const float* outw = (const float*)d_in[8];
    const float* outb = (const float*)d_in[9];
    float* out = (float*)d_out;

    char* ws = (char*)d_ws;
    float* wc       = (float*)ws;                       // 128*3072*4 = 1.5 MB
    float* y        = (float*)(ws + 1572864);           // 16384*16*4 = 1 MB
    int*   bucketArr= (int*)(ws + 1572864 + 1048576);   // 8*16384*4 = 512 KB
    int*   counts   = (int*)(ws + 1572864 + 1048576 + 524288);

    (void)hipMemsetAsync(counts, 0, 32, stream);
    k_combine<<<384, 256, 0, stream>>>(l1w, l1fw, wc);
    k_bucket<<<BATCH / 256, 256, 0, stream>>>(ls, counts, bucketArr);
    // max blocks = 16384/16 + 7 (ceil rounding across 8 buckets)
    k_gemm<<<1031, 256, 0, stream>>>(x, wc, l1b, l1fb, bucketArr, counts, y);
    k_tail<<<BATCH * 32 / 256, 256, 0, stream>>>(y, ls, l2w, l2b, outw, outb, out);
}